// Round 1
// baseline (1253.708 us; speedup 1.0000x reference)
//
#include <hip/hip_runtime.h>

#define N_NODES 10000
#define N_EDGES 160000
#define DIM 512

// ---------------------------------------------------------------------------
// Kernel 1: edge scatter.  agg[src] += h[dst]  (fp32 atomics), deg[src] += 1.
// One wave (64 lanes) per edge; two float4 loads per lane = full 512-f row.
// h is 20 MB -> L3-resident, gather reads mostly cache hits.
// ---------------------------------------------------------------------------
__global__ __launch_bounds__(256) void scatter_edges(
    const float* __restrict__ h, const int* __restrict__ edge_index,
    float* __restrict__ agg, float* __restrict__ deg)
{
    int gid  = blockIdx.x * blockDim.x + threadIdx.x;
    int e    = gid >> 6;
    int lane = gid & 63;
    if (e >= N_EDGES) return;
    int src = edge_index[e];
    int dst = edge_index[N_EDGES + e];
    const float4* hrow = (const float4*)(h + (size_t)dst * DIM);
    float* arow = agg + (size_t)src * DIM;
#pragma unroll
    for (int c = 0; c < 2; ++c) {
        int d4 = lane + c * 64;           // float4 index 0..127
        float4 v = hrow[d4];
        atomicAdd(&arow[d4 * 4 + 0], v.x);
        atomicAdd(&arow[d4 * 4 + 1], v.y);
        atomicAdd(&arow[d4 * 4 + 2], v.z);
        atomicAdd(&arow[d4 * 4 + 3], v.w);
    }
    if (lane == 0) atomicAdd(&deg[src], 1.0f);
}

// ---------------------------------------------------------------------------
// Kernel 2: fused GEMM  x = h + relu( [h | agg/deg] @ [Wself | Wneigh]^T + b )
// C tile 32 nodes x 128 cols per 256-thread block, 4x4 microtile/thread,
// KC=32 K-chunks staged in LDS.  fp32 vector FMA (no fp32 MFMA on CDNA4).
// ---------------------------------------------------------------------------
#define TM 32
#define TN 128
#define KC 32

__global__ __launch_bounds__(256) void fused_gemm(
    const float* __restrict__ h, const float* __restrict__ agg,
    const float* __restrict__ deg,
    const float* __restrict__ Wself, const float* __restrict__ bself,
    const float* __restrict__ Wneigh, const float* __restrict__ bneigh,
    float* __restrict__ xout)
{
    __shared__ float As[TM][KC + 4];   // +4 pad keeps 16B alignment, breaks pow2 stride
    __shared__ float Bs[KC][TN + 4];
    __shared__ float sInv[TM];
    __shared__ float sHas[TM];

    const int t     = threadIdx.x;
    const int node0 = blockIdx.x * TM;
    const int col0  = blockIdx.y * TN;

    if (t < TM) {
        int n = node0 + t;
        float d = (n < N_NODES) ? deg[n] : 0.0f;
        sInv[t] = 1.0f / fmaxf(d, 1.0f);
        sHas[t] = (d > 0.0f) ? 1.0f : 0.0f;   // reference: bias only if deg>0
    }
    __syncthreads();

    const int tx = t & 31;    // col group: cols tx*4 .. tx*4+3
    const int ty = t >> 5;    // node group: nodes ty*4 .. ty*4+3

    const int a_n  = t >> 3;        // 0..31  node for A staging
    const int a_k4 = (t & 7) * 4;   // 0,4,..28  k offset for A staging

    float acc[4][4];
#pragma unroll
    for (int i = 0; i < 4; ++i)
#pragma unroll
        for (int j = 0; j < 4; ++j) acc[i][j] = 0.0f;

    for (int k0 = 0; k0 < 2 * DIM; k0 += KC) {
        // ---- stage A: X[node][k],  X = [h | agg*inv_deg] ----
        {
            int n = node0 + a_n;
            float4 v = make_float4(0.f, 0.f, 0.f, 0.f);
            if (n < N_NODES) {
                if (k0 < DIM) {
                    v = *(const float4*)(h + (size_t)n * DIM + k0 + a_k4);
                } else {
                    v = *(const float4*)(agg + (size_t)n * DIM + (k0 - DIM) + a_k4);
                    float sc = sInv[a_n];
                    v.x *= sc; v.y *= sc; v.z *= sc; v.w *= sc;
                }
            }
            *(float4*)&As[a_n][a_k4] = v;
        }
        // ---- stage B: Wcat[col][k] -> Bs[k][col] (transposed store) ----
        const float* Wb = (k0 < DIM) ? Wself : Wneigh;
        const int kk = k0 & (DIM - 1);
#pragma unroll
        for (int it = 0; it < 4; ++it) {
            int idx = it * 256 + t;
            int col = idx >> 3;           // 0..127
            int k4  = (idx & 7) * 4;      // 0..28
            float4 w = *(const float4*)(Wb + (size_t)(col0 + col) * DIM + kk + k4);
            Bs[k4 + 0][col] = w.x;
            Bs[k4 + 1][col] = w.y;
            Bs[k4 + 2][col] = w.z;
            Bs[k4 + 3][col] = w.w;
        }
        __syncthreads();

#pragma unroll
        for (int k = 0; k < KC; ++k) {
            float a0 = As[ty * 4 + 0][k];
            float a1 = As[ty * 4 + 1][k];
            float a2 = As[ty * 4 + 2][k];
            float a3 = As[ty * 4 + 3][k];
            float4 bv = *(const float4*)&Bs[k][tx * 4];
            acc[0][0] += a0 * bv.x; acc[0][1] += a0 * bv.y; acc[0][2] += a0 * bv.z; acc[0][3] += a0 * bv.w;
            acc[1][0] += a1 * bv.x; acc[1][1] += a1 * bv.y; acc[1][2] += a1 * bv.z; acc[1][3] += a1 * bv.w;
            acc[2][0] += a2 * bv.x; acc[2][1] += a2 * bv.y; acc[2][2] += a2 * bv.z; acc[2][3] += a2 * bv.w;
            acc[3][0] += a3 * bv.x; acc[3][1] += a3 * bv.y; acc[3][2] += a3 * bv.z; acc[3][3] += a3 * bv.w;
        }
        __syncthreads();
    }

    // ---- epilogue: bias + relu + residual ----
#pragma unroll
    for (int i = 0; i < 4; ++i) {
        int n = node0 + ty * 4 + i;
        if (n >= N_NODES) continue;
        float hb = sHas[ty * 4 + i];
        int c = col0 + tx * 4;
        float4 bs = *(const float4*)(bself + c);
        float4 bn = *(const float4*)(bneigh + c);
        float4 hv = *(const float4*)(h + (size_t)n * DIM + c);
        float4 o;
        o.x = fmaxf(acc[i][0] + bs.x + hb * bn.x, 0.f) + hv.x;
        o.y = fmaxf(acc[i][1] + bs.y + hb * bn.y, 0.f) + hv.y;
        o.z = fmaxf(acc[i][2] + bs.z + hb * bn.z, 0.f) + hv.z;
        o.w = fmaxf(acc[i][3] + bs.w + hb * bn.w, 0.f) + hv.w;
        *(float4*)(xout + (size_t)n * DIM + c) = o;
    }
}

// ---------------------------------------------------------------------------
// Kernel 3: in-place row LayerNorm, one 256-thread block per node row.
// ---------------------------------------------------------------------------
__global__ __launch_bounds__(256) void ln_kernel(
    float* __restrict__ x, const float* __restrict__ g, const float* __restrict__ b)
{
    __shared__ float red[8];
    int n = blockIdx.x;
    float* row = x + (size_t)n * DIM;
    int t = threadIdx.x;
    float2 v = *(float2*)(row + t * 2);
    float s  = v.x + v.y;
    float sq = v.x * v.x + v.y * v.y;
#pragma unroll
    for (int off = 32; off >= 1; off >>= 1) {
        s  += __shfl_xor(s, off);
        sq += __shfl_xor(sq, off);
    }
    int wave = t >> 6;
    if ((t & 63) == 0) { red[wave] = s; red[4 + wave] = sq; }
    __syncthreads();
    s  = red[0] + red[1] + red[2] + red[3];
    sq = red[4] + red[5] + red[6] + red[7];
    float mean = s * (1.0f / DIM);
    float var  = sq * (1.0f / DIM) - mean * mean;
    float rstd = rsqrtf(var + 1e-5f);
    float2 gv = *(const float2*)(g + t * 2);
    float2 bv = *(const float2*)(b + t * 2);
    float2 o;
    o.x = (v.x - mean) * rstd * gv.x + bv.x;
    o.y = (v.y - mean) * rstd * gv.y + bv.y;
    *(float2*)(row + t * 2) = o;
}

// ---------------------------------------------------------------------------
extern "C" void kernel_launch(void* const* d_in, const int* in_sizes, int n_in,
                              void* d_out, int out_size, void* d_ws, size_t ws_size,
                              hipStream_t stream)
{
    const float* h      = (const float*)d_in[0];
    const int*   eidx   = (const int*)d_in[1];
    const float* Wself  = (const float*)d_in[2];
    const float* bself  = (const float*)d_in[3];
    const float* Wneigh = (const float*)d_in[4];
    const float* bneigh = (const float*)d_in[5];
    const float* gamma  = (const float*)d_in[6];
    const float* beta   = (const float*)d_in[7];
    float* out = (float*)d_out;

    float* agg = (float*)d_ws;                       // N_NODES * DIM f32
    float* deg = agg + (size_t)N_NODES * DIM;        // N_NODES f32

    hipMemsetAsync(d_ws, 0, (size_t)(N_NODES * DIM + N_NODES) * sizeof(float), stream);

    scatter_edges<<<(N_EDGES * 64) / 256, 256, 0, stream>>>(h, eidx, agg, deg);

    dim3 g((N_NODES + TM - 1) / TM, DIM / TN);
    fused_gemm<<<g, 256, 0, stream>>>(h, agg, deg, Wself, bself, Wneigh, bneigh, out);

    ln_kernel<<<N_NODES, 256, 0, stream>>>(out, gamma, beta);
}

// Round 2
// 267.877 us; speedup vs baseline: 4.6802x; 4.6802x over previous
//
#include <hip/hip_runtime.h>

#define N_NODES 10000
#define N_EDGES 160000
#define DIM 512

// ---------------------------------------------------------------------------
// CSR build pass 1: histogram of src.
// ---------------------------------------------------------------------------
__global__ __launch_bounds__(256) void hist_kernel(
    const int* __restrict__ eidx, int* __restrict__ cnt)
{
    int e = blockIdx.x * 256 + threadIdx.x;
    if (e < N_EDGES) atomicAdd(&cnt[eidx[e]], 1);
}

// ---------------------------------------------------------------------------
// CSR build pass 2: exclusive prefix scan (single 1024-thread workgroup).
// row_ptr[0]=0, row_ptr[i+1]=row_ptr[i]+cnt[i].  10000 elems -> 10 chunks.
// ---------------------------------------------------------------------------
__global__ __launch_bounds__(1024) void scan_kernel(
    const int* __restrict__ cnt, int* __restrict__ row_ptr)
{
    __shared__ int wsum[16];
    __shared__ int carry_s;
    int t = threadIdx.x;
    if (t == 0) { carry_s = 0; row_ptr[0] = 0; }
    __syncthreads();
    for (int base = 0; base < N_NODES; base += 1024) {
        int i = base + t;
        int v = (i < N_NODES) ? cnt[i] : 0;
        int lane = t & 63;
        int incl = v;
#pragma unroll
        for (int off = 1; off < 64; off <<= 1) {
            int u = __shfl_up(incl, off);
            if (lane >= off) incl += u;
        }
        int wave = t >> 6;
        if (lane == 63) wsum[wave] = incl;
        __syncthreads();
        int woff = 0;
#pragma unroll
        for (int w = 0; w < 16; ++w)
            if (w < wave) woff += wsum[w];
        int inclusive = carry_s + woff + incl;
        if (i < N_NODES) row_ptr[i + 1] = inclusive;
        __syncthreads();
        if (t == 1023) carry_s = inclusive;
        __syncthreads();
    }
}

// ---------------------------------------------------------------------------
// CSR build pass 3: scatter dst indices into per-src buckets.
// ---------------------------------------------------------------------------
__global__ __launch_bounds__(256) void fill_kernel(
    const int* __restrict__ eidx, const int* __restrict__ row_ptr,
    int* __restrict__ fill, int* __restrict__ col)
{
    int e = blockIdx.x * 256 + threadIdx.x;
    if (e >= N_EDGES) return;
    int s = eidx[e];
    int d = eidx[N_EDGES + e];
    int p = atomicAdd(&fill[s], 1);
    col[row_ptr[s] + p] = d;
}

// ---------------------------------------------------------------------------
// Gather-aggregate: one wave per node.  Each lane owns 8 of 512 columns
// (two float4 slots: lane and lane+64).  h rows are 2KB contiguous reads,
// L3-resident (h = 20MB).  agg row written exactly once -> no fp atomics.
// Edge list broadcast from registers via shfl (deg<=64 common case).
// ---------------------------------------------------------------------------
__global__ __launch_bounds__(256) void gather_agg(
    const float* __restrict__ h, const int* __restrict__ row_ptr,
    const int* __restrict__ col, float* __restrict__ agg,
    float* __restrict__ deg)
{
    int gid  = blockIdx.x * 256 + threadIdx.x;
    int n    = gid >> 6;
    int lane = gid & 63;
    if (n >= N_NODES) return;
    int b = row_ptr[n];
    int e = row_ptr[n + 1];
    int d = e - b;

    // prefetch up to 64 edge targets into one register, broadcast via shfl
    int myc = (b + lane < e) ? col[b + lane] : 0;

    float4 a0 = make_float4(0.f, 0.f, 0.f, 0.f);
    float4 a1 = make_float4(0.f, 0.f, 0.f, 0.f);
    int nk = d < 64 ? d : 64;
    for (int k = 0; k < nk; ++k) {
        int dst = __shfl(myc, k);
        const float4* hr = (const float4*)(h + (size_t)dst * DIM);
        float4 v0 = hr[lane];
        float4 v1 = hr[lane + 64];
        a0.x += v0.x; a0.y += v0.y; a0.z += v0.z; a0.w += v0.w;
        a1.x += v1.x; a1.y += v1.y; a1.z += v1.z; a1.w += v1.w;
    }
    for (int k = b + 64; k < e; ++k) {   // rare tail (deg > 64)
        int dst = col[k];
        const float4* hr = (const float4*)(h + (size_t)dst * DIM);
        float4 v0 = hr[lane];
        float4 v1 = hr[lane + 64];
        a0.x += v0.x; a0.y += v0.y; a0.z += v0.z; a0.w += v0.w;
        a1.x += v1.x; a1.y += v1.y; a1.z += v1.z; a1.w += v1.w;
    }
    float4* ar = (float4*)(agg + (size_t)n * DIM);
    ar[lane]      = a0;
    ar[lane + 64] = a1;
    if (lane == 0) deg[n] = (float)d;
}

// ---------------------------------------------------------------------------
// Fused GEMM  x = h + relu( [h | agg/deg] @ [Wself | Wneigh]^T + b )
// C tile 32 nodes x 128 cols per 256-thread block, 4x4 microtile/thread,
// KC=32 K-chunks staged in LDS.  fp32 vector FMA (no fp32 MFMA on CDNA4).
// ---------------------------------------------------------------------------
#define TM 32
#define TN 128
#define KC 32

__global__ __launch_bounds__(256) void fused_gemm(
    const float* __restrict__ h, const float* __restrict__ agg,
    const float* __restrict__ deg,
    const float* __restrict__ Wself, const float* __restrict__ bself,
    const float* __restrict__ Wneigh, const float* __restrict__ bneigh,
    float* __restrict__ xout)
{
    __shared__ float As[TM][KC + 4];
    __shared__ float Bs[KC][TN + 4];
    __shared__ float sInv[TM];
    __shared__ float sHas[TM];

    const int t     = threadIdx.x;
    const int node0 = blockIdx.x * TM;
    const int col0  = blockIdx.y * TN;

    if (t < TM) {
        int n = node0 + t;
        float d = (n < N_NODES) ? deg[n] : 0.0f;
        sInv[t] = 1.0f / fmaxf(d, 1.0f);
        sHas[t] = (d > 0.0f) ? 1.0f : 0.0f;   // reference: bias only if deg>0
    }
    __syncthreads();

    const int tx = t & 31;
    const int ty = t >> 5;

    const int a_n  = t >> 3;
    const int a_k4 = (t & 7) * 4;

    float acc[4][4];
#pragma unroll
    for (int i = 0; i < 4; ++i)
#pragma unroll
        for (int j = 0; j < 4; ++j) acc[i][j] = 0.0f;

    for (int k0 = 0; k0 < 2 * DIM; k0 += KC) {
        {
            int n = node0 + a_n;
            float4 v = make_float4(0.f, 0.f, 0.f, 0.f);
            if (n < N_NODES) {
                if (k0 < DIM) {
                    v = *(const float4*)(h + (size_t)n * DIM + k0 + a_k4);
                } else {
                    v = *(const float4*)(agg + (size_t)n * DIM + (k0 - DIM) + a_k4);
                    float sc = sInv[a_n];
                    v.x *= sc; v.y *= sc; v.z *= sc; v.w *= sc;
                }
            }
            *(float4*)&As[a_n][a_k4] = v;
        }
        const float* Wb = (k0 < DIM) ? Wself : Wneigh;
        const int kk = k0 & (DIM - 1);
#pragma unroll
        for (int it = 0; it < 4; ++it) {
            int idx = it * 256 + t;
            int c   = idx >> 3;
            int k4  = (idx & 7) * 4;
            float4 w = *(const float4*)(Wb + (size_t)(col0 + c) * DIM + kk + k4);
            Bs[k4 + 0][c] = w.x;
            Bs[k4 + 1][c] = w.y;
            Bs[k4 + 2][c] = w.z;
            Bs[k4 + 3][c] = w.w;
        }
        __syncthreads();

#pragma unroll
        for (int k = 0; k < KC; ++k) {
            float a0 = As[ty * 4 + 0][k];
            float a1 = As[ty * 4 + 1][k];
            float a2 = As[ty * 4 + 2][k];
            float a3 = As[ty * 4 + 3][k];
            float4 bv = *(const float4*)&Bs[k][tx * 4];
            acc[0][0] += a0 * bv.x; acc[0][1] += a0 * bv.y; acc[0][2] += a0 * bv.z; acc[0][3] += a0 * bv.w;
            acc[1][0] += a1 * bv.x; acc[1][1] += a1 * bv.y; acc[1][2] += a1 * bv.z; acc[1][3] += a1 * bv.w;
            acc[2][0] += a2 * bv.x; acc[2][1] += a2 * bv.y; acc[2][2] += a2 * bv.z; acc[2][3] += a2 * bv.w;
            acc[3][0] += a3 * bv.x; acc[3][1] += a3 * bv.y; acc[3][2] += a3 * bv.z; acc[3][3] += a3 * bv.w;
        }
        __syncthreads();
    }

#pragma unroll
    for (int i = 0; i < 4; ++i) {
        int n = node0 + ty * 4 + i;
        if (n >= N_NODES) continue;
        float hb = sHas[ty * 4 + i];
        int c = col0 + tx * 4;
        float4 bs = *(const float4*)(bself + c);
        float4 bn = *(const float4*)(bneigh + c);
        float4 hv = *(const float4*)(h + (size_t)n * DIM + c);
        float4 o;
        o.x = fmaxf(acc[i][0] + bs.x + hb * bn.x, 0.f) + hv.x;
        o.y = fmaxf(acc[i][1] + bs.y + hb * bn.y, 0.f) + hv.y;
        o.z = fmaxf(acc[i][2] + bs.z + hb * bn.z, 0.f) + hv.z;
        o.w = fmaxf(acc[i][3] + bs.w + hb * bn.w, 0.f) + hv.w;
        *(float4*)(xout + (size_t)n * DIM + c) = o;
    }
}

// ---------------------------------------------------------------------------
// In-place row LayerNorm, one 256-thread block per node row.
// ---------------------------------------------------------------------------
__global__ __launch_bounds__(256) void ln_kernel(
    float* __restrict__ x, const float* __restrict__ g, const float* __restrict__ b)
{
    __shared__ float red[8];
    int n = blockIdx.x;
    float* row = x + (size_t)n * DIM;
    int t = threadIdx.x;
    float2 v = *(float2*)(row + t * 2);
    float s  = v.x + v.y;
    float sq = v.x * v.x + v.y * v.y;
#pragma unroll
    for (int off = 32; off >= 1; off >>= 1) {
        s  += __shfl_xor(s, off);
        sq += __shfl_xor(sq, off);
    }
    int wave = t >> 6;
    if ((t & 63) == 0) { red[wave] = s; red[4 + wave] = sq; }
    __syncthreads();
    s  = red[0] + red[1] + red[2] + red[3];
    sq = red[4] + red[5] + red[6] + red[7];
    float mean = s * (1.0f / DIM);
    float var  = sq * (1.0f / DIM) - mean * mean;
    float rstd = rsqrtf(var + 1e-5f);
    float2 gv = *(const float2*)(g + t * 2);
    float2 bv = *(const float2*)(b + t * 2);
    float2 o;
    o.x = (v.x - mean) * rstd * gv.x + bv.x;
    o.y = (v.y - mean) * rstd * gv.y + bv.y;
    *(float2*)(row + t * 2) = o;
}

// ---------------------------------------------------------------------------
extern "C" void kernel_launch(void* const* d_in, const int* in_sizes, int n_in,
                              void* d_out, int out_size, void* d_ws, size_t ws_size,
                              hipStream_t stream)
{
    const float* h      = (const float*)d_in[0];
    const int*   eidx   = (const int*)d_in[1];
    const float* Wself  = (const float*)d_in[2];
    const float* bself  = (const float*)d_in[3];
    const float* Wneigh = (const float*)d_in[4];
    const float* bneigh = (const float*)d_in[5];
    const float* gamma  = (const float*)d_in[6];
    const float* beta   = (const float*)d_in[7];
    float* out = (float*)d_out;

    // workspace layout
    float* agg     = (float*)d_ws;                          // N*DIM f32
    float* deg     = agg + (size_t)N_NODES * DIM;           // N f32
    int*   cnt     = (int*)(deg + N_NODES);                 // N int
    int*   fill    = cnt + N_NODES;                         // N int
    int*   row_ptr = fill + N_NODES;                        // N+1 int
    int*   col     = row_ptr + (N_NODES + 1);               // E int

    // zero only cnt+fill (contiguous)
    hipMemsetAsync(cnt, 0, 2 * N_NODES * sizeof(int), stream);

    hist_kernel<<<(N_EDGES + 255) / 256, 256, 0, stream>>>(eidx, cnt);
    scan_kernel<<<1, 1024, 0, stream>>>(cnt, row_ptr);
    fill_kernel<<<(N_EDGES + 255) / 256, 256, 0, stream>>>(eidx, row_ptr, fill, col);
    gather_agg<<<(N_NODES * 64 + 255) / 256, 256, 0, stream>>>(h, row_ptr, col, agg, deg);

    dim3 g((N_NODES + TM - 1) / TM, DIM / TN);
    fused_gemm<<<g, 256, 0, stream>>>(h, agg, deg, Wself, bself, Wneigh, bneigh, out);

    ln_kernel<<<N_NODES, 256, 0, stream>>>(out, gamma, beta);
}

// Round 4
// 201.902 us; speedup vs baseline: 6.2095x; 1.3268x over previous
//
#include <hip/hip_runtime.h>

#define N_NODES 10000
#define N_PAD   10016          // padded to multiple of 32 for MFMA tiles
#define N_EDGES 160000
#define DIM     512
#define KDIM    1024           // concatenated K = [h | neigh]

typedef __attribute__((ext_vector_type(8))) short bf16x8;
typedef __attribute__((ext_vector_type(4))) float f32x4;

static __device__ __forceinline__ ushort f2bf(float f) {
    union { float f; unsigned u; } x; x.f = f;
    unsigned u = x.u + 0x7fff + ((x.u >> 16) & 1);   // round-to-nearest-even
    return (ushort)(u >> 16);
}

// ---------------------------------------------------------------------------
// CSR build pass 1: histogram of src.
// ---------------------------------------------------------------------------
__global__ __launch_bounds__(256) void hist_kernel(
    const int* __restrict__ eidx, int* __restrict__ cnt)
{
    int e = blockIdx.x * 256 + threadIdx.x;
    if (e < N_EDGES) atomicAdd(&cnt[eidx[e]], 1);
}

// ---------------------------------------------------------------------------
// CSR build pass 2: exclusive prefix scan (single 1024-thread workgroup).
// ---------------------------------------------------------------------------
__global__ __launch_bounds__(1024) void scan_kernel(
    const int* __restrict__ cnt, int* __restrict__ row_ptr)
{
    __shared__ int wsum[16];
    __shared__ int carry_s;
    int t = threadIdx.x;
    if (t == 0) { carry_s = 0; row_ptr[0] = 0; }
    __syncthreads();
    for (int base = 0; base < N_NODES; base += 1024) {
        int i = base + t;
        int v = (i < N_NODES) ? cnt[i] : 0;
        int lane = t & 63;
        int incl = v;
#pragma unroll
        for (int off = 1; off < 64; off <<= 1) {
            int u = __shfl_up(incl, off);
            if (lane >= off) incl += u;
        }
        int wave = t >> 6;
        if (lane == 63) wsum[wave] = incl;
        __syncthreads();
        int woff = 0;
#pragma unroll
        for (int w = 0; w < 16; ++w)
            if (w < wave) woff += wsum[w];
        int inclusive = carry_s + woff + incl;
        if (i < N_NODES) row_ptr[i + 1] = inclusive;
        __syncthreads();
        if (t == 1023) carry_s = inclusive;
        __syncthreads();
    }
}

// ---------------------------------------------------------------------------
// CSR build pass 3: scatter dst indices into per-src buckets.
// ---------------------------------------------------------------------------
__global__ __launch_bounds__(256) void fill_kernel(
    const int* __restrict__ eidx, const int* __restrict__ row_ptr,
    int* __restrict__ fill, int* __restrict__ col)
{
    int e = blockIdx.x * 256 + threadIdx.x;
    if (e >= N_EDGES) return;
    int s = eidx[e];
    int d = eidx[N_EDGES + e];
    int p = atomicAdd(&fill[s], 1);
    col[row_ptr[s] + p] = d;
}

// ---------------------------------------------------------------------------
// conv_x: left half of X = bf16(h); pad rows (n >= N_NODES) fully zeroed.
// ---------------------------------------------------------------------------
__global__ __launch_bounds__(256) void conv_x(
    const float* __restrict__ h, ushort* __restrict__ X)
{
    int idx = blockIdx.x * 256 + threadIdx.x;
    int n  = idx >> 7;
    int k8 = idx & 127;
    if (n >= N_PAD) return;
    ushort* dst = X + (size_t)n * KDIM + k8 * 8;
    if (n >= N_NODES) {                      // zero pad row (full 1024)
        ushort4 z = {0, 0, 0, 0};
        *(ushort4*)dst = z;
        *(ushort4*)(dst + 4) = z;
        return;
    }
    if (k8 >= 64) return;                    // right half written by gather
    const float* src = h + (size_t)n * DIM + k8 * 8;
    float4 v0 = *(const float4*)src;
    float4 v1 = *(const float4*)(src + 4);
    ushort4 o0 = { f2bf(v0.x), f2bf(v0.y), f2bf(v0.z), f2bf(v0.w) };
    ushort4 o1 = { f2bf(v1.x), f2bf(v1.y), f2bf(v1.z), f2bf(v1.w) };
    *(ushort4*)dst = o0;
    *(ushort4*)(dst + 4) = o1;
}

// ---------------------------------------------------------------------------
// conv_w: Wc[c][k] = bf16( k<512 ? Wself[c][k] : Wneigh[c][k-512] )
// ---------------------------------------------------------------------------
__global__ __launch_bounds__(256) void conv_w(
    const float* __restrict__ Wself, const float* __restrict__ Wneigh,
    ushort* __restrict__ Wc)
{
    int idx = blockIdx.x * 256 + threadIdx.x;     // over 512*128
    int c  = idx >> 7;
    int k8 = idx & 127;
    const float* src = (k8 < 64) ? (Wself + (size_t)c * DIM + k8 * 8)
                                 : (Wneigh + (size_t)c * DIM + (k8 - 64) * 8);
    float4 v0 = *(const float4*)src;
    float4 v1 = *(const float4*)(src + 4);
    ushort* dst = Wc + (size_t)c * KDIM + k8 * 8;
    ushort4 o0 = { f2bf(v0.x), f2bf(v0.y), f2bf(v0.z), f2bf(v0.w) };
    ushort4 o1 = { f2bf(v1.x), f2bf(v1.y), f2bf(v1.z), f2bf(v1.w) };
    *(ushort4*)dst = o0;
    *(ushort4*)(dst + 4) = o1;
}

// ---------------------------------------------------------------------------
// Gather-aggregate: one wave per node; lane owns cols {lane*4..+3, 256+lane*4..+3}.
// Row sum scaled by 1/max(deg,1), converted bf16, written into X right half.
// ---------------------------------------------------------------------------
__global__ __launch_bounds__(256) void gather_agg(
    const float* __restrict__ h, const int* __restrict__ row_ptr,
    const int* __restrict__ col, ushort* __restrict__ X,
    float* __restrict__ deg)
{
    int gid  = blockIdx.x * 256 + threadIdx.x;
    int n    = gid >> 6;
    int lane = gid & 63;
    if (n >= N_NODES) return;
    int b = row_ptr[n];
    int e = row_ptr[n + 1];
    int d = e - b;

    int myc = (b + lane < e) ? col[b + lane] : 0;

    float4 a0 = make_float4(0.f, 0.f, 0.f, 0.f);
    float4 a1 = make_float4(0.f, 0.f, 0.f, 0.f);
    int nk = d < 64 ? d : 64;
    for (int k = 0; k < nk; ++k) {
        int dst = __shfl(myc, k);
        const float4* hr = (const float4*)(h + (size_t)dst * DIM);
        float4 v0 = hr[lane];
        float4 v1 = hr[lane + 64];
        a0.x += v0.x; a0.y += v0.y; a0.z += v0.z; a0.w += v0.w;
        a1.x += v1.x; a1.y += v1.y; a1.z += v1.z; a1.w += v1.w;
    }
    for (int k = b + 64; k < e; ++k) {   // rare tail (deg > 64)
        int dst = col[k];
        const float4* hr = (const float4*)(h + (size_t)dst * DIM);
        float4 v0 = hr[lane];
        float4 v1 = hr[lane + 64];
        a0.x += v0.x; a0.y += v0.y; a0.z += v0.z; a0.w += v0.w;
        a1.x += v1.x; a1.y += v1.y; a1.z += v1.z; a1.w += v1.w;
    }
    float inv = 1.0f / fmaxf((float)d, 1.0f);
    ushort* xr = X + (size_t)n * KDIM + DIM;
    ushort4 o0 = { f2bf(a0.x * inv), f2bf(a0.y * inv), f2bf(a0.z * inv), f2bf(a0.w * inv) };
    ushort4 o1 = { f2bf(a1.x * inv), f2bf(a1.y * inv), f2bf(a1.z * inv), f2bf(a1.w * inv) };
    *(ushort4*)(xr + lane * 4)       = o0;
    *(ushort4*)(xr + 256 + lane * 4) = o1;
    if (lane == 0) deg[n] = (float)d;
}

// ---------------------------------------------------------------------------
// MFMA GEMM + fused epilogue + LayerNorm.
// Block: 256 thr (4 waves), 32 rows x 512 cols; wave w -> cols [w*128, w*128+128).
// out = LN( h + relu( X @ Wc^T + bself + (deg>0)*bneigh ) )
// ---------------------------------------------------------------------------
__global__ __launch_bounds__(256) void mfma_gemm_ln(
    const ushort* __restrict__ X, const ushort* __restrict__ Wc,
    const float* __restrict__ deg, const float* __restrict__ h,
    const float* __restrict__ bself, const float* __restrict__ bneigh,
    const float* __restrict__ gamma, const float* __restrict__ beta,
    float* __restrict__ out)
{
    __shared__ float xs[32][516];    // stride 516: 2-way bank alias only (free)
    __shared__ float bs_s[DIM];
    __shared__ float bn_s[DIM];
    __shared__ float hb_s[32];

    const int t    = threadIdx.x;
    const int lane = t & 63;
    const int wave = t >> 6;
    const int row0 = blockIdx.x * 32;
    const int col0 = wave * 128;
    const int fr   = lane & 15;
    const int fk   = (lane >> 4) * 8;

    if (t < 128) {
        *(float4*)&bs_s[t * 4] = *(const float4*)&bself[t * 4];
        *(float4*)&bn_s[t * 4] = *(const float4*)&bneigh[t * 4];
    }
    if (t < 32) {
        int n = row0 + t;
        hb_s[t] = (n < N_NODES && deg[n] > 0.0f) ? 1.0f : 0.0f;
    }

    f32x4 acc[2][8];
#pragma unroll
    for (int i = 0; i < 2; ++i)
#pragma unroll
        for (int j = 0; j < 8; ++j)
            acc[i][j] = (f32x4){0.f, 0.f, 0.f, 0.f};

    const ushort* xrow = X + (size_t)(row0 + fr) * KDIM + fk;
    const ushort* wrow = Wc + (size_t)(col0 + fr) * KDIM + fk;

    for (int k0 = 0; k0 < KDIM; k0 += 32) {
        bf16x8 a0 = *(const bf16x8*)(xrow + k0);
        bf16x8 a1 = *(const bf16x8*)(xrow + 16 * KDIM + k0);
        bf16x8 b[8];
#pragma unroll
        for (int j = 0; j < 8; ++j)
            b[j] = *(const bf16x8*)(wrow + (size_t)j * 16 * KDIM + k0);
#pragma unroll
        for (int j = 0; j < 8; ++j) {
            acc[0][j] = __builtin_amdgcn_mfma_f32_16x16x32_bf16(a0, b[j], acc[0][j], 0, 0, 0);
            acc[1][j] = __builtin_amdgcn_mfma_f32_16x16x32_bf16(a1, b[j], acc[1][j], 0, 0, 0);
        }
    }

    __syncthreads();   // bs_s/bn_s/hb_s visible

    // epilogue: relu(acc + bself + hb*bneigh) -> xs
    const int r0 = (lane >> 4) * 4;
#pragma unroll
    for (int i = 0; i < 2; ++i) {
#pragma unroll
        for (int r = 0; r < 4; ++r) {
            int rr = i * 16 + r0 + r;
            float hb = hb_s[rr];
#pragma unroll
            for (int j = 0; j < 8; ++j) {
                int c = col0 + j * 16 + fr;
                xs[rr][c] = fmaxf(acc[i][j][r] + bs_s[c] + hb * bn_s[c], 0.0f);
            }
        }
    }
    __syncthreads();

    // LN: row rr = t>>3, cols (t&7)*64 .. +63 per thread (8 lanes per row)
    const int rr = t >> 3;
    const int cs = (t & 7) * 64;
    const int n  = row0 + rr;
    const bool valid = (n < N_NODES);
    float x[64];
    float s = 0.f, sq = 0.f;
    const float* hrow = h + (size_t)n * DIM + cs;
#pragma unroll
    for (int m = 0; m < 16; ++m) {
        float4 hv = valid ? *(const float4*)(hrow + m * 4)
                          : make_float4(0.f, 0.f, 0.f, 0.f);
        float4 xv = *(const float4*)&xs[rr][cs + m * 4];
        float v0 = xv.x + hv.x, v1 = xv.y + hv.y, v2 = xv.z + hv.z, v3 = xv.w + hv.w;
        x[m * 4 + 0] = v0; x[m * 4 + 1] = v1; x[m * 4 + 2] = v2; x[m * 4 + 3] = v3;
        s  += v0 + v1 + v2 + v3;
        sq += v0 * v0 + v1 * v1 + v2 * v2 + v3 * v3;
    }
#pragma unroll
    for (int off = 1; off <= 4; off <<= 1) {
        s  += __shfl_xor(s, off);
        sq += __shfl_xor(sq, off);
    }
    float mean = s * (1.0f / DIM);
    float var  = sq * (1.0f / DIM) - mean * mean;
    float rstd = rsqrtf(var + 1e-5f);
    if (valid) {
        float* orow = out + (size_t)n * DIM + cs;
#pragma unroll
        for (int m = 0; m < 16; ++m) {
            float4 gv = *(const float4*)(gamma + cs + m * 4);
            float4 bv = *(const float4*)(beta + cs + m * 4);
            float4 o;
            o.x = (x[m * 4 + 0] - mean) * rstd * gv.x + bv.x;
            o.y = (x[m * 4 + 1] - mean) * rstd * gv.y + bv.y;
            o.z = (x[m * 4 + 2] - mean) * rstd * gv.z + bv.z;
            o.w = (x[m * 4 + 3] - mean) * rstd * gv.w + bv.w;
            *(float4*)(orow + m * 4) = o;
        }
    }
}

// ---------------------------------------------------------------------------
extern "C" void kernel_launch(void* const* d_in, const int* in_sizes, int n_in,
                              void* d_out, int out_size, void* d_ws, size_t ws_size,
                              hipStream_t stream)
{
    const float* h      = (const float*)d_in[0];
    const int*   eidx   = (const int*)d_in[1];
    const float* Wself  = (const float*)d_in[2];
    const float* bself  = (const float*)d_in[3];
    const float* Wneigh = (const float*)d_in[4];
    const float* bneigh = (const float*)d_in[5];
    const float* gamma  = (const float*)d_in[6];
    const float* beta   = (const float*)d_in[7];
    float* out = (float*)d_out;

    ushort* X   = (ushort*)d_ws;                          // N_PAD*KDIM bf16
    ushort* Wc  = X + (size_t)N_PAD * KDIM;               // 512*KDIM bf16
    float* deg  = (float*)(Wc + (size_t)DIM * KDIM);      // N f32
    int* cnt    = (int*)(deg + N_NODES);
    int* fill   = cnt + N_NODES;
    int* row_ptr = fill + N_NODES;
    int* col    = row_ptr + (N_NODES + 1);

    hipMemsetAsync(cnt, 0, 2 * N_NODES * sizeof(int), stream);

    conv_w<<<(DIM * 128) / 256, 256, 0, stream>>>(Wself, Wneigh, Wc);
    conv_x<<<(N_PAD * 128) / 256, 256, 0, stream>>>(h, X);

    hist_kernel<<<(N_EDGES + 255) / 256, 256, 0, stream>>>(eidx, cnt);
    scan_kernel<<<1, 1024, 0, stream>>>(cnt, row_ptr);
    fill_kernel<<<(N_EDGES + 255) / 256, 256, 0, stream>>>(eidx, row_ptr, fill, col);
    gather_agg<<<(N_NODES * 64) / 256, 256, 0, stream>>>(h, row_ptr, col, X, deg);

    mfma_gemm_ln<<<(N_PAD / 32), 256, 0, stream>>>(X, Wc, deg, h, bself, bneigh,
                                                   gamma, beta, out);
}

// Round 5
// 186.392 us; speedup vs baseline: 6.7262x; 1.0832x over previous
//
#include <hip/hip_runtime.h>

#define N_NODES 10000
#define N_PAD   10016          // padded to multiple of 32 for MFMA tiles
#define N_EDGES 160000
#define DIM     512
#define KDIM    1024           // concatenated K = [h | neigh]

typedef __attribute__((ext_vector_type(8))) short bf16x8;
typedef __attribute__((ext_vector_type(4))) float f32x4;

static __device__ __forceinline__ ushort f2bf(float f) {
    union { float f; unsigned u; } x; x.f = f;
    unsigned u = x.u + 0x7fff + ((x.u >> 16) & 1);   // round-to-nearest-even
    return (ushort)(u >> 16);
}
static __device__ __forceinline__ float b2f(ushort u) {
    union { unsigned u; float f; } x; x.u = ((unsigned)u) << 16; return x.f;
}

// ---------------------------------------------------------------------------
// CSR build pass 1: histogram of src.
// ---------------------------------------------------------------------------
__global__ __launch_bounds__(256) void hist_kernel(
    const int* __restrict__ eidx, int* __restrict__ cnt)
{
    int e = blockIdx.x * 256 + threadIdx.x;
    if (e < N_EDGES) atomicAdd(&cnt[eidx[e]], 1);
}

// ---------------------------------------------------------------------------
// CSR build pass 2: exclusive prefix scan (single 1024-thread workgroup).
// ---------------------------------------------------------------------------
__global__ __launch_bounds__(1024) void scan_kernel(
    const int* __restrict__ cnt, int* __restrict__ row_ptr)
{
    __shared__ int wsum[16];
    __shared__ int carry_s;
    int t = threadIdx.x;
    if (t == 0) { carry_s = 0; row_ptr[0] = 0; }
    __syncthreads();
    for (int base = 0; base < N_NODES; base += 1024) {
        int i = base + t;
        int v = (i < N_NODES) ? cnt[i] : 0;
        int lane = t & 63;
        int incl = v;
#pragma unroll
        for (int off = 1; off < 64; off <<= 1) {
            int u = __shfl_up(incl, off);
            if (lane >= off) incl += u;
        }
        int wave = t >> 6;
        if (lane == 63) wsum[wave] = incl;
        __syncthreads();
        int woff = 0;
#pragma unroll
        for (int w = 0; w < 16; ++w)
            if (w < wave) woff += wsum[w];
        int inclusive = carry_s + woff + incl;
        if (i < N_NODES) row_ptr[i + 1] = inclusive;
        __syncthreads();
        if (t == 1023) carry_s = inclusive;
        __syncthreads();
    }
}

// ---------------------------------------------------------------------------
// CSR build pass 3: scatter dst indices into per-src buckets.
// ---------------------------------------------------------------------------
__global__ __launch_bounds__(256) void fill_kernel(
    const int* __restrict__ eidx, const int* __restrict__ row_ptr,
    int* __restrict__ fill, int* __restrict__ col)
{
    int e = blockIdx.x * 256 + threadIdx.x;
    if (e >= N_EDGES) return;
    int s = eidx[e];
    int d = eidx[N_EDGES + e];
    int p = atomicAdd(&fill[s], 1);
    col[row_ptr[s] + p] = d;
}

// ---------------------------------------------------------------------------
// conv_x: left half of X = bf16(h); pad rows (n >= N_NODES) fully zeroed.
// ---------------------------------------------------------------------------
__global__ __launch_bounds__(256) void conv_x(
    const float* __restrict__ h, ushort* __restrict__ X)
{
    int idx = blockIdx.x * 256 + threadIdx.x;
    int n  = idx >> 7;
    int k8 = idx & 127;
    if (n >= N_PAD) return;
    ushort* dst = X + (size_t)n * KDIM + k8 * 8;
    if (n >= N_NODES) {                      // zero pad row (full 1024)
        ushort4 z = {0, 0, 0, 0};
        *(ushort4*)dst = z;
        *(ushort4*)(dst + 4) = z;
        return;
    }
    if (k8 >= 64) return;                    // right half written by gather
    const float* src = h + (size_t)n * DIM + k8 * 8;
    float4 v0 = *(const float4*)src;
    float4 v1 = *(const float4*)(src + 4);
    ushort4 o0 = { f2bf(v0.x), f2bf(v0.y), f2bf(v0.z), f2bf(v0.w) };
    ushort4 o1 = { f2bf(v1.x), f2bf(v1.y), f2bf(v1.z), f2bf(v1.w) };
    *(ushort4*)dst = o0;
    *(ushort4*)(dst + 4) = o1;
}

// ---------------------------------------------------------------------------
// conv_w: Wc[c][k] = bf16( k<512 ? Wself[c][k] : Wneigh[c][k-512] )
// ---------------------------------------------------------------------------
__global__ __launch_bounds__(256) void conv_w(
    const float* __restrict__ Wself, const float* __restrict__ Wneigh,
    ushort* __restrict__ Wc)
{
    int idx = blockIdx.x * 256 + threadIdx.x;     // over 512*128
    int c  = idx >> 7;
    int k8 = idx & 127;
    const float* src = (k8 < 64) ? (Wself + (size_t)c * DIM + k8 * 8)
                                 : (Wneigh + (size_t)c * DIM + (k8 - 64) * 8);
    float4 v0 = *(const float4*)src;
    float4 v1 = *(const float4*)(src + 4);
    ushort* dst = Wc + (size_t)c * KDIM + k8 * 8;
    ushort4 o0 = { f2bf(v0.x), f2bf(v0.y), f2bf(v0.z), f2bf(v0.w) };
    ushort4 o1 = { f2bf(v1.x), f2bf(v1.y), f2bf(v1.z), f2bf(v1.w) };
    *(ushort4*)dst = o0;
    *(ushort4*)(dst + 4) = o1;
}

// ---------------------------------------------------------------------------
// Gather-aggregate (bf16 source): one wave per node; lane owns cols
// lane*8 .. lane*8+7.  Reads bf16 rows from X left half (1 KB/row, half the
// f32 traffic), sums in f32, scales by 1/max(deg,1), writes bf16 into X
// right half.
// ---------------------------------------------------------------------------
__global__ __launch_bounds__(256) void gather_agg(
    const int* __restrict__ row_ptr, const int* __restrict__ col,
    ushort* __restrict__ X, float* __restrict__ deg)
{
    int gid  = blockIdx.x * 256 + threadIdx.x;
    int n    = gid >> 6;
    int lane = gid & 63;
    if (n >= N_NODES) return;
    int b = row_ptr[n];
    int e = row_ptr[n + 1];
    int d = e - b;

    int myc = (b + lane < e) ? col[b + lane] : 0;

    float s0 = 0.f, s1 = 0.f, s2 = 0.f, s3 = 0.f;
    float s4 = 0.f, s5 = 0.f, s6 = 0.f, s7 = 0.f;
    int nk = d < 64 ? d : 64;
    for (int k = 0; k < nk; ++k) {
        int dst = __shfl(myc, k);
        bf16x8 v = *(const bf16x8*)(X + (size_t)dst * KDIM + lane * 8);
        s0 += b2f((ushort)v[0]); s1 += b2f((ushort)v[1]);
        s2 += b2f((ushort)v[2]); s3 += b2f((ushort)v[3]);
        s4 += b2f((ushort)v[4]); s5 += b2f((ushort)v[5]);
        s6 += b2f((ushort)v[6]); s7 += b2f((ushort)v[7]);
    }
    for (int k = b + 64; k < e; ++k) {   // rare tail (deg > 64)
        int dst = col[k];
        bf16x8 v = *(const bf16x8*)(X + (size_t)dst * KDIM + lane * 8);
        s0 += b2f((ushort)v[0]); s1 += b2f((ushort)v[1]);
        s2 += b2f((ushort)v[2]); s3 += b2f((ushort)v[3]);
        s4 += b2f((ushort)v[4]); s5 += b2f((ushort)v[5]);
        s6 += b2f((ushort)v[6]); s7 += b2f((ushort)v[7]);
    }
    float inv = 1.0f / fmaxf((float)d, 1.0f);
    ushort* xr = X + (size_t)n * KDIM + DIM + lane * 8;
    ushort4 o0 = { f2bf(s0 * inv), f2bf(s1 * inv), f2bf(s2 * inv), f2bf(s3 * inv) };
    ushort4 o1 = { f2bf(s4 * inv), f2bf(s5 * inv), f2bf(s6 * inv), f2bf(s7 * inv) };
    *(ushort4*)xr       = o0;
    *(ushort4*)(xr + 4) = o1;
    if (lane == 0) deg[n] = (float)d;
}

// ---------------------------------------------------------------------------
// MFMA GEMM + fused epilogue + LayerNorm.
// Block: 512 thr (8 waves), tile 32 rows x 512 cols; wave w -> cols [w*64,+64).
// Named-register fragments, depth-1 software prefetch in the K loop.
// out = LN( h + relu( X @ Wc^T + bself + (deg>0)*bneigh ) )
// ---------------------------------------------------------------------------
#define MFMA(A, B, C) __builtin_amdgcn_mfma_f32_16x16x32_bf16(A, B, C, 0, 0, 0)

__global__ __launch_bounds__(512) void mfma_gemm_ln(
    const ushort* __restrict__ X, const ushort* __restrict__ Wc,
    const float* __restrict__ deg, const float* __restrict__ h,
    const float* __restrict__ bself, const float* __restrict__ bneigh,
    const float* __restrict__ gamma, const float* __restrict__ beta,
    float* __restrict__ out)
{
    __shared__ float xs[32][516];    // stride 516: 2-way bank alias only (free)
    __shared__ float bs_s[DIM];
    __shared__ float bn_s[DIM];
    __shared__ float hb_s[32];

    const int t    = threadIdx.x;
    const int lane = t & 63;
    const int wave = t >> 6;
    const int row0 = blockIdx.x * 32;
    const int col0 = wave * 64;
    const int fr   = lane & 15;
    const int fk   = (lane >> 4) * 8;

    if (t < 128) {
        *(float4*)&bs_s[t * 4] = *(const float4*)&bself[t * 4];
        *(float4*)&bn_s[t * 4] = *(const float4*)&bneigh[t * 4];
    }
    if (t < 32) {
        int n = row0 + t;
        hb_s[t] = (n < N_NODES && deg[n] > 0.0f) ? 1.0f : 0.0f;
    }

    f32x4 acc00 = {0.f,0.f,0.f,0.f}, acc01 = acc00, acc02 = acc00, acc03 = acc00;
    f32x4 acc10 = acc00, acc11 = acc00, acc12 = acc00, acc13 = acc00;

    const ushort* xp = X  + (size_t)(row0 + fr) * KDIM + fk;
    const ushort* wp = Wc + (size_t)(col0 + fr) * KDIM + fk;

    bf16x8 a0 = *(const bf16x8*)(xp);
    bf16x8 a1 = *(const bf16x8*)(xp + 16 * KDIM);
    bf16x8 b0 = *(const bf16x8*)(wp);
    bf16x8 b1 = *(const bf16x8*)(wp + 16 * KDIM);
    bf16x8 b2 = *(const bf16x8*)(wp + 32 * KDIM);
    bf16x8 b3 = *(const bf16x8*)(wp + 48 * KDIM);

    for (int k0 = 32; k0 < KDIM; k0 += 32) {
        // prefetch next K-step (issued before this step's MFMAs)
        bf16x8 na0 = *(const bf16x8*)(xp + k0);
        bf16x8 na1 = *(const bf16x8*)(xp + k0 + 16 * KDIM);
        bf16x8 nb0 = *(const bf16x8*)(wp + k0);
        bf16x8 nb1 = *(const bf16x8*)(wp + k0 + 16 * KDIM);
        bf16x8 nb2 = *(const bf16x8*)(wp + k0 + 32 * KDIM);
        bf16x8 nb3 = *(const bf16x8*)(wp + k0 + 48 * KDIM);

        acc00 = MFMA(a0, b0, acc00); acc01 = MFMA(a0, b1, acc01);
        acc02 = MFMA(a0, b2, acc02); acc03 = MFMA(a0, b3, acc03);
        acc10 = MFMA(a1, b0, acc10); acc11 = MFMA(a1, b1, acc11);
        acc12 = MFMA(a1, b2, acc12); acc13 = MFMA(a1, b3, acc13);

        a0 = na0; a1 = na1; b0 = nb0; b1 = nb1; b2 = nb2; b3 = nb3;
    }
    acc00 = MFMA(a0, b0, acc00); acc01 = MFMA(a0, b1, acc01);
    acc02 = MFMA(a0, b2, acc02); acc03 = MFMA(a0, b3, acc03);
    acc10 = MFMA(a1, b0, acc10); acc11 = MFMA(a1, b1, acc11);
    acc12 = MFMA(a1, b2, acc12); acc13 = MFMA(a1, b3, acc13);

    __syncthreads();   // bs_s/bn_s/hb_s visible

    // epilogue: relu(acc + bself + hb*bneigh) -> xs
    const int r0 = (lane >> 4) * 4;
    const int c0 = col0 + fr;
#pragma unroll
    for (int r = 0; r < 4; ++r) {
        int rr0 = r0 + r, rr1 = 16 + r0 + r;
        float hb0 = hb_s[rr0], hb1 = hb_s[rr1];
        xs[rr0][c0     ] = fmaxf(acc00[r] + bs_s[c0     ] + hb0 * bn_s[c0     ], 0.f);
        xs[rr0][c0 + 16] = fmaxf(acc01[r] + bs_s[c0 + 16] + hb0 * bn_s[c0 + 16], 0.f);
        xs[rr0][c0 + 32] = fmaxf(acc02[r] + bs_s[c0 + 32] + hb0 * bn_s[c0 + 32], 0.f);
        xs[rr0][c0 + 48] = fmaxf(acc03[r] + bs_s[c0 + 48] + hb0 * bn_s[c0 + 48], 0.f);
        xs[rr1][c0     ] = fmaxf(acc10[r] + bs_s[c0     ] + hb1 * bn_s[c0     ], 0.f);
        xs[rr1][c0 + 16] = fmaxf(acc11[r] + bs_s[c0 + 16] + hb1 * bn_s[c0 + 16], 0.f);
        xs[rr1][c0 + 32] = fmaxf(acc12[r] + bs_s[c0 + 32] + hb1 * bn_s[c0 + 32], 0.f);
        xs[rr1][c0 + 48] = fmaxf(acc13[r] + bs_s[c0 + 48] + hb1 * bn_s[c0 + 48], 0.f);
    }
    __syncthreads();

    // LN: 16 threads per row; row rr = t>>4, cols (t&15)*32 .. +31
    const int rr = t >> 4;
    const int cs = (t & 15) * 32;
    const int n  = row0 + rr;
    const bool valid = (n < N_NODES);
    float x[32];
    float s = 0.f, sq = 0.f;
    const float* hrow = h + (size_t)n * DIM + cs;
#pragma unroll
    for (int m = 0; m < 8; ++m) {
        float4 hv = valid ? *(const float4*)(hrow + m * 4)
                          : make_float4(0.f, 0.f, 0.f, 0.f);
        float4 xv = *(const float4*)&xs[rr][cs + m * 4];
        float v0 = xv.x + hv.x, v1 = xv.y + hv.y, v2 = xv.z + hv.z, v3 = xv.w + hv.w;
        x[m * 4 + 0] = v0; x[m * 4 + 1] = v1; x[m * 4 + 2] = v2; x[m * 4 + 3] = v3;
        s  += v0 + v1 + v2 + v3;
        sq += v0 * v0 + v1 * v1 + v2 * v2 + v3 * v3;
    }
#pragma unroll
    for (int off = 1; off <= 8; off <<= 1) {
        s  += __shfl_xor(s, off);
        sq += __shfl_xor(sq, off);
    }
    float mean = s * (1.0f / DIM);
    float var  = sq * (1.0f / DIM) - mean * mean;
    float rstd = rsqrtf(var + 1e-5f);
    if (valid) {
        float* orow = out + (size_t)n * DIM + cs;
#pragma unroll
        for (int m = 0; m < 8; ++m) {
            float4 gv = *(const float4*)(gamma + cs + m * 4);
            float4 bv = *(const float4*)(beta + cs + m * 4);
            float4 o;
            o.x = (x[m * 4 + 0] - mean) * rstd * gv.x + bv.x;
            o.y = (x[m * 4 + 1] - mean) * rstd * gv.y + bv.y;
            o.z = (x[m * 4 + 2] - mean) * rstd * gv.z + bv.z;
            o.w = (x[m * 4 + 3] - mean) * rstd * gv.w + bv.w;
            *(float4*)(orow + m * 4) = o;
        }
    }
}

// ---------------------------------------------------------------------------
extern "C" void kernel_launch(void* const* d_in, const int* in_sizes, int n_in,
                              void* d_out, int out_size, void* d_ws, size_t ws_size,
                              hipStream_t stream)
{
    const float* h      = (const float*)d_in[0];
    const int*   eidx   = (const int*)d_in[1];
    const float* Wself  = (const float*)d_in[2];
    const float* bself  = (const float*)d_in[3];
    const float* Wneigh = (const float*)d_in[4];
    const float* bneigh = (const float*)d_in[5];
    const float* gamma  = (const float*)d_in[6];
    const float* beta   = (const float*)d_in[7];
    float* out = (float*)d_out;

    ushort* X   = (ushort*)d_ws;                          // N_PAD*KDIM bf16
    ushort* Wc  = X + (size_t)N_PAD * KDIM;               // 512*KDIM bf16
    float* deg  = (float*)(Wc + (size_t)DIM * KDIM);      // N f32
    int* cnt    = (int*)(deg + N_NODES);
    int* fill   = cnt + N_NODES;
    int* row_ptr = fill + N_NODES;
    int* col    = row_ptr + (N_NODES + 1);

    hipMemsetAsync(cnt, 0, 2 * N_NODES * sizeof(int), stream);

    conv_w<<<(DIM * 128) / 256, 256, 0, stream>>>(Wself, Wneigh, Wc);
    conv_x<<<(N_PAD * 128) / 256, 256, 0, stream>>>(h, X);

    hist_kernel<<<(N_EDGES + 255) / 256, 256, 0, stream>>>(eidx, cnt);
    scan_kernel<<<1, 1024, 0, stream>>>(cnt, row_ptr);
    fill_kernel<<<(N_EDGES + 255) / 256, 256, 0, stream>>>(eidx, row_ptr, fill, col);
    gather_agg<<<(N_NODES * 64) / 256, 256, 0, stream>>>(row_ptr, col, X, deg);

    mfma_gemm_ln<<<(N_PAD / 32), 512, 0, stream>>>(X, Wc, deg, h, bself, bneigh,
                                                   gamma, beta, out);
}